// Round 8
// baseline (402.738 us; speedup 1.0000x reference)
//
#include <hip/hip_runtime.h>
#include <hip/hip_cooperative_groups.h>
#include <math.h>

namespace cg = cooperative_groups;

#define N_NODES 20000
#define N_EDGES 320000

__device__ __forceinline__ float lrelu(float x){ return x > 0.f ? x : 0.02f*x; }

__device__ __forceinline__ unsigned short f2bf(float f){
  union { float f; unsigned u; } v; v.f = f;
  unsigned r = (v.u + 0x7FFFu + ((v.u >> 16) & 1u)) >> 16;
  return (unsigned short)r;
}
__device__ __forceinline__ float bf2f(unsigned short u){
  union { unsigned u; float f; } v; v.u = ((unsigned)u) << 16; return v.f;
}

typedef __attribute__((ext_vector_type(8))) short bf16x8;
typedef __attribute__((ext_vector_type(4))) float f32x4;
typedef __attribute__((ext_vector_type(8))) unsigned short u16x8;

// ---------------- CSR build ----------------
__global__ void k_zero(int* counts, float* deg){
  int i = blockIdx.x*blockDim.x + threadIdx.x;
  if (i < N_NODES){ counts[i]=0; deg[i]=0.f; }
}

// fused: h->bf16 convert + dst-degree count + x->float4 pack
__global__ void k_cnt_cvt(const int* __restrict__ dst, int* __restrict__ counts,
                          const float* __restrict__ h, unsigned short* __restrict__ h_bf,
                          const float* __restrict__ x, float4* __restrict__ x4){
  int i = blockIdx.x*256 + threadIdx.x;      // exactly 640000 threads
  float4 v = reinterpret_cast<const float4*>(h)[i];
  ushort4 o;
  o.x = f2bf(v.x); o.y = f2bf(v.y); o.z = f2bf(v.z); o.w = f2bf(v.w);
  reinterpret_cast<ushort4*>(h_bf)[i] = o;
  if (i < N_EDGES) atomicAdd(&counts[dst[i]], 1);
  if (i < N_NODES) x4[i] = make_float4(x[3*i], x[3*i+1], x[3*i+2], 0.f);
}

__global__ void k_scan(int* __restrict__ counts, int* __restrict__ rowptr){
  __shared__ int part[256];
  int tid = threadIdx.x;
  const int CH = (N_NODES + 255)/256; // 79
  int b = tid*CH, e = b+CH; if (e > N_NODES) e = N_NODES;
  int s = 0;
  for (int i=b;i<e;++i) s += counts[i];
  part[tid] = s; __syncthreads();
  if (tid==0){
    int run=0;
    for (int i=0;i<256;++i){ int t=part[i]; part[i]=run; run+=t; }
    rowptr[N_NODES]=run;
  }
  __syncthreads();
  int off = part[tid];
  for (int i=b;i<e;++i){ rowptr[i]=off; off += counts[i]; counts[i]=0; }
}

__global__ void k_fill(const int* __restrict__ src, const int* __restrict__ dst,
                       const int* __restrict__ rowptr, int* __restrict__ cursor,
                       int* __restrict__ srcS, int* __restrict__ dstS){
  int e = blockIdx.x*blockDim.x + threadIdx.x;
  if (e < N_EDGES){
    int d = dst[e];
    int pos = atomicAdd(&cursor[d],1);
    int idx = rowptr[d] + pos;
    srcS[idx] = src[e];
    dstS[idx] = d;
  }
}

// ---------------- weight prep (once): edge-weight pack + bf16 transposes --------
// wbuf layout (floats): [0,640) eW1 rows 0..4 ; [640,768) base = eb1 + sum_{j>=5} eW1[j]
// (valid: for j>=5, exp(-d2*1e-2j) deviates from 1 by <2e-7 in fp32 — negligible);
// [768,896) eW2 ; [896,1216) rU padded 16x20 ; [1216,1536) rW2 padded 16x20
__global__ void k_prep(const float* __restrict__ eW1, const float* __restrict__ eb1,
                       const float* __restrict__ eW2v, const float* __restrict__ rW1,
                       const float* __restrict__ rW2, const float* __restrict__ fW1,
                       const float* __restrict__ fW2,
                       float* __restrict__ wbuf,
                       unsigned short* __restrict__ WTbig,
                       unsigned short* __restrict__ WTf2){
  int i = blockIdx.x*blockDim.x + threadIdx.x;   // 1536 + 81920 + 16384 = 99840
  if (i < 1536){
    float v;
    if (i < 640) v = eW1[i];
    else if (i < 768){
      int c = i-640; float s = eb1[c];
      for (int j=5;j<10;++j) s += eW1[j*128+c];
      v = s;
    } else if (i < 896) v = eW2v[i-768];
    else if (i < 1216){ int k = i-896;  int l = k/20, jj = k%20;
      v = (jj<16) ? rW1[256*256 + l*16 + jj] : 0.f;
    } else            { int k = i-1216; int l = k/20, jj = k%20;
      v = (jj<16) ? rW2[l*16 + jj] : 0.f;
    }
    wbuf[i] = v;
  } else if (i < 1536 + 81920){
    int j = i - 1536;
    int row = j >> 7, k = j & 127;
    float v = (row < 256) ? rW1[(size_t)k*256 + row]
            : (row < 512) ? rW1[(size_t)(128+k)*256 + (row-256)]
                          : fW1[(size_t)k*128 + (row-512)];
    WTbig[j] = f2bf(v);
  } else if (i < 1536 + 81920 + 16384){
    int j = i - 1536 - 81920; int n = j >> 7, k = j & 127;
    WTf2[j] = f2bf(fW2[(size_t)k*128 + n]);
  }
}

// ---------------- MFMA bf16 GEMM: 64x64 tile, 4 waves, 16x16x32 ----------------
// mode 0 (N=640): col<256 -> Pb=bf16(v+b0[col]); col<512 -> Qb=bf16(v);
//                 else Tb=bf16(lrelu(v+b1[col-512]))
// mode 1 (N=128): O1 = v + b0[col] (f32); also outHspec = coef[0]*(v+b0[col])
__global__ __launch_bounds__(256) void k_gemm_mfma(
    const unsigned short* __restrict__ Abf, const unsigned short* __restrict__ WT,
    const float* __restrict__ b0, const float* __restrict__ b1, int mode,
    float* __restrict__ O1, unsigned short* __restrict__ Pb,
    unsigned short* __restrict__ Qb, unsigned short* __restrict__ Tb,
    const float* __restrict__ coefp, float* __restrict__ outHspec)
{
  __shared__ char lA[16384];
  __shared__ char lB[16384];
  int t = threadIdx.x;
  int rbase = blockIdx.x * 64;
  int cbase = blockIdx.y * 64;
  #pragma unroll
  for (int i=0;i<4;++i){
    int c = t + i*256;            // chunk 0..1023, 16B each
    int row = c >> 4, c8 = c & 15;
    int grow = rbase + row; if (grow > N_NODES-1) grow = N_NODES-1;
    float4 av = *reinterpret_cast<const float4*>(Abf + (size_t)grow*128 + c8*8);
    *reinterpret_cast<float4*>(lA + (((row<<8) + (c8<<4)) ^ ((row&7)<<4))) = av;
    float4 wv = *reinterpret_cast<const float4*>(WT + (size_t)(cbase+row)*128 + c8*8);
    *reinterpret_cast<float4*>(lB + (((row<<8) + (c8<<4)) ^ ((row&7)<<4))) = wv;
  }
  __syncthreads();
  int l = t & 63, w = t >> 6;
  int lr = l & 15;
  int lkb = ((l >> 4) << 3) * 2;          // k byte offset: 0,16,32,48
  int sxor = (lr & 7) << 4;
  f32x4 acc[4];
  #pragma unroll
  for (int tm=0;tm<4;++tm) acc[tm] = (f32x4){0.f,0.f,0.f,0.f};
  #pragma unroll
  for (int ks=0; ks<4; ++ks){
    int kb = ks*64 + lkb;
    bf16x8 bv = *reinterpret_cast<const bf16x8*>(lB + (((((w<<4)+lr)<<8) + kb) ^ sxor));
    #pragma unroll
    for (int tm=0;tm<4;++tm){
      bf16x8 av = *reinterpret_cast<const bf16x8*>(lA + (((((tm<<4)+lr)<<8) + kb) ^ sxor));
      acc[tm] = __builtin_amdgcn_mfma_f32_16x16x32_bf16(av, bv, acc[tm], 0, 0, 0);
    }
  }
  int col = cbase + (w<<4) + lr;
  float bval;
  if (mode==0) bval = (col < 256) ? b0[col] : (col >= 512 ? b1[col-512] : 0.f);
  else         bval = b0[col];
  float c0 = (mode==1) ? coefp[0] : 0.f;
  int rsub = (l >> 4) << 2;
  #pragma unroll
  for (int tm=0;tm<4;++tm){
    #pragma unroll
    for (int r=0;r<4;++r){
      int grow = rbase + (tm<<4) + rsub + r;
      if (grow < N_NODES){
        float v = acc[tm][r];
        if (mode==0){
          if (col < 256)      Pb[(size_t)grow*256 + col]       = f2bf(v + bval);
          else if (col < 512) Qb[(size_t)grow*256 + col - 256] = f2bf(v);
          else                Tb[(size_t)grow*128 + col - 512] = f2bf(lrelu(v + bval));
        } else {
          float vb = v + bval;
          O1[(size_t)grow*128 + col] = vb;
          outHspec[(size_t)grow*128 + col] = c0 * vb;
        }
      }
    }
  }
}

// ---------------- per-edge: 16 lanes/edge, weights in LDS ----------------
// launch_bounds (256,4): cap 128 VGPR — 64 VGPR actual, no spill (round 6 lesson:
// (256,6) forced 85-VGPR cap -> scratch spill -> 1 GB/dispatch HBM traffic).
__global__ __launch_bounds__(256, 4) void k_edge(
    const int* __restrict__ srcS, const int* __restrict__ dstS,
    const float4* __restrict__ x4,
    const unsigned short* __restrict__ P, const unsigned short* __restrict__ Q,
    const float* __restrict__ wbuf,
    const float* __restrict__ eb2, const float* __restrict__ rb2,
    const int* __restrict__ flags,
    float* __restrict__ deg, float4* __restrict__ rxw)
{
  __shared__ float sw[1536];
  int tid = threadIdx.x;
  for (int i = tid; i < 1536; i += 256) sw[i] = wbuf[i];
  __syncthreads();
  int l = tid & 15;            // lane in 16-lane edge group
  int grp = tid >> 4;          // 0..15 edge slot in block
  float base_r[8], eW2v[8];
  #pragma unroll
  for (int i=0;i<4;++i){
    float2 b = *reinterpret_cast<const float2*>(&sw[640 + 2*l + 32*i]);
    float2 w = *reinterpret_cast<const float2*>(&sw[768 + 2*l + 32*i]);
    base_r[2*i]=b.x; base_r[2*i+1]=b.y; eW2v[2*i]=w.x; eW2v[2*i+1]=w.y;
  }
  float eb2v = eb2[0], rb2v = rb2[0];
  const bool needDeg = flags[0] != 0;   // deg/normE consumed only if any Ax step runs
  for (int e = blockIdx.x*16 + grp; e < N_EDGES; e += gridDim.x*16){
    int s = srcS[e], d = dstS[e];
    const u16x8* Ps = reinterpret_cast<const u16x8*>(P + (size_t)s*256 + l*16);
    const u16x8* Qd = reinterpret_cast<const u16x8*>(Q + (size_t)d*256 + l*16);
    u16x8 pa = Ps[0], pb = Ps[1];
    u16x8 qa = Qd[0], qb = Qd[1];
    float4 xs = x4[s], xd = x4[d];
    float dx0 = xs.x-xd.x, dx1 = xs.y-xd.y, dx2 = xs.z-xd.z;
    float d2 = dx0*dx0 + dx1*dx1 + dx2*dx2;
    float h[8];
    #pragma unroll
    for (int i=0;i<8;++i) h[i] = base_r[i];
    const float IS[5] = {1.f,1e-2f,1e-4f,1e-6f,1e-8f};
    #pragma unroll
    for (int j=0;j<5;++j){
      float gj = __expf(-d2*IS[j]);
      #pragma unroll
      for (int i=0;i<4;++i){
        float2 w2 = *reinterpret_cast<const float2*>(&sw[j*128 + 2*l + 32*i]);
        h[2*i]   += gj*w2.x;
        h[2*i+1] += gj*w2.y;
      }
    }
    float part = 0.f;
    #pragma unroll
    for (int i=0;i<8;++i) part += lrelu(h[i])*eW2v[i];
    part += __shfl_xor(part,1); part += __shfl_xor(part,2);
    part += __shfl_xor(part,4); part += __shfl_xor(part,8);
    float wlap = part + eb2v; wlap = wlap > 0.f ? wlap : 0.f;
    // r-dot over this lane's 16 contiguous cols; rU/rW2 from padded LDS (2-way max)
    float acc = 0.f;
    {
      float4 u = *reinterpret_cast<const float4*>(&sw[896 + l*20]);
      float4 w = *reinterpret_cast<const float4*>(&sw[1216 + l*20]);
      acc += lrelu(bf2f((unsigned short)pa[0])+bf2f((unsigned short)qa[0])+wlap*u.x)*w.x;
      acc += lrelu(bf2f((unsigned short)pa[1])+bf2f((unsigned short)qa[1])+wlap*u.y)*w.y;
      acc += lrelu(bf2f((unsigned short)pa[2])+bf2f((unsigned short)qa[2])+wlap*u.z)*w.z;
      acc += lrelu(bf2f((unsigned short)pa[3])+bf2f((unsigned short)qa[3])+wlap*u.w)*w.w;
    }
    {
      float4 u = *reinterpret_cast<const float4*>(&sw[896 + l*20 + 4]);
      float4 w = *reinterpret_cast<const float4*>(&sw[1216 + l*20 + 4]);
      acc += lrelu(bf2f((unsigned short)pa[4])+bf2f((unsigned short)qa[4])+wlap*u.x)*w.x;
      acc += lrelu(bf2f((unsigned short)pa[5])+bf2f((unsigned short)qa[5])+wlap*u.y)*w.y;
      acc += lrelu(bf2f((unsigned short)pa[6])+bf2f((unsigned short)qa[6])+wlap*u.z)*w.z;
      acc += lrelu(bf2f((unsigned short)pa[7])+bf2f((unsigned short)qa[7])+wlap*u.w)*w.w;
    }
    {
      float4 u = *reinterpret_cast<const float4*>(&sw[896 + l*20 + 8]);
      float4 w = *reinterpret_cast<const float4*>(&sw[1216 + l*20 + 8]);
      acc += lrelu(bf2f((unsigned short)pb[0])+bf2f((unsigned short)qb[0])+wlap*u.x)*w.x;
      acc += lrelu(bf2f((unsigned short)pb[1])+bf2f((unsigned short)qb[1])+wlap*u.y)*w.y;
      acc += lrelu(bf2f((unsigned short)pb[2])+bf2f((unsigned short)qb[2])+wlap*u.z)*w.z;
      acc += lrelu(bf2f((unsigned short)pb[3])+bf2f((unsigned short)qb[3])+wlap*u.w)*w.w;
    }
    {
      float4 u = *reinterpret_cast<const float4*>(&sw[896 + l*20 + 12]);
      float4 w = *reinterpret_cast<const float4*>(&sw[1216 + l*20 + 12]);
      acc += lrelu(bf2f((unsigned short)pb[4])+bf2f((unsigned short)qb[4])+wlap*u.x)*w.x;
      acc += lrelu(bf2f((unsigned short)pb[5])+bf2f((unsigned short)qb[5])+wlap*u.y)*w.y;
      acc += lrelu(bf2f((unsigned short)pb[6])+bf2f((unsigned short)qb[6])+wlap*u.z)*w.z;
      acc += lrelu(bf2f((unsigned short)pb[7])+bf2f((unsigned short)qb[7])+wlap*u.w)*w.w;
    }
    acc += __shfl_xor(acc,1); acc += __shfl_xor(acc,2);
    acc += __shfl_xor(acc,4); acc += __shfl_xor(acc,8);
    if (l==0){
      float r = acc + rb2v;
      if (needDeg) atomicAdd(&deg[s], wlap);
      rxw[e] = make_float4(r*dx0, r*dx1, r*dx2, wlap);
    }
  }
}

// ---------------- fused post pass: agg (blocks 0..4999) + normE (5000..6249) ----
__global__ __launch_bounds__(256) void k_post(const int* __restrict__ rowptr,
    const float4* __restrict__ rxw, const float* __restrict__ x,
    float* __restrict__ outX,
    const int* __restrict__ srcS, const int* __restrict__ dstS,
    const float* __restrict__ deg, const int* __restrict__ flags,
    float* __restrict__ norm)
{
  if (blockIdx.x < 5000){
    int lane = threadIdx.x & 63;
    int v = blockIdx.x*4 + (threadIdx.x>>6);
    if (v >= N_NODES) return;
    int b = rowptr[v], e = rowptr[v+1];
    float a0=0.f,a1=0.f,a2=0.f;
    for (int i=b+lane;i<e;i+=64){ float4 f = rxw[i]; a0+=f.x; a1+=f.y; a2+=f.z; }
    #pragma unroll
    for (int m=1;m<64;m<<=1){ a0+=__shfl_xor(a0,m); a1+=__shfl_xor(a1,m); a2+=__shfl_xor(a2,m); }
    if (lane==0){
      int cnt = e-b; if (cnt < 1) cnt = 1;
      float inv = 1.0f/(float)cnt;
      outX[v*3+0] = x[v*3+0] + a0*inv;
      outX[v*3+1] = x[v*3+1] + a1*inv;
      outX[v*3+2] = x[v*3+2] + a2*inv;
    }
  } else {
    if (!flags[0]) return;   // normE consumed only by Ax steps
    int e = (blockIdx.x-5000)*256 + threadIdx.x;
    if (e < N_EDGES){
      float ds = deg[srcS[e]], dd = deg[dstS[e]];
      float is = ds > 0.f ? rsqrtf(ds) : 0.f;
      float id = dd > 0.f ? rsqrtf(dd) : 0.f;
      norm[e] = is * rxw[e].w * id;
    }
  }
}

// polynomial coefficients + run flags
// flags[j] (j>=1): run step j iff sum_{m>=j}|coef|>0
// flags[0]       : run step 0 iff sum_{m>=1}|coef|>0 (else GEMM's spec write
//                  outH = coef0*h0 is already exact). Doubles as "deg/normE needed".
// flags[16+j]    : zin identically zero at step j (sum_{m>j}|coef| == 0) -> scaleOnly
__global__ void k_coef(const float* __restrict__ temp, float* __restrict__ coef,
                       int* __restrict__ flags,
                       float* __restrict__ outT1, float* __restrict__ outT2){
  if (threadIdx.x == 0 && blockIdx.x == 0){
    const double binom[11] = {1,10,45,120,210,252,210,120,45,10,1};
    double a[11]; for (int j=0;j<11;++j) a[j]=0.0;
    for (int m=0;m<=10;++m){
      double p[11]; p[0]=1.0; for (int j=1;j<11;++j) p[j]=0.0;
      for (int r2=0;r2<10-m;++r2) for (int j=10;j>=1;--j) p[j]+=p[j-1];
      for (int r2=0;r2<m;++r2)    for (int j=10;j>=1;--j) p[j]-=p[j-1];
      float t = temp[m];
      double c = (binom[m]/1024.0) * (t > 0.f ? (double)t : 0.0);
      for (int j=0;j<11;++j) a[j]+=c*p[j];
    }
    for (int j=0;j<11;++j) coef[j]=(float)a[j];
    double sIn = 0.0;
    for (int j=10;j>=0;--j){
      double sOut = sIn + fabs(a[j]);
      flags[j]    = (j==0) ? ((sIn != 0.0) ? 1 : 0) : ((sOut != 0.0) ? 1 : 0);
      flags[16+j] = (sIn  == 0.0) ? 1 : 0;
      sIn = sOut;
    }
  }
  int i = threadIdx.x;
  if (blockIdx.x==0 && i < 11){ float t = temp[i]; t = t>0.f?t:0.f; outT1[i]=t; outT2[i]=t; }
}

// ---------------- cooperative Horner: all Ax steps in ONE launch ----------------
// zout = coef[j]*h0 + A*zin per active step, grid.sync() between steps.
// Control flow is uniform across all blocks (flags/coef are global, identical).
// temp=ones case: all flags 0 -> immediate exit (replaces 11 no-op dispatches).
__global__ __launch_bounds__(256) void k_horner(
    const int* __restrict__ rowptr, const int* __restrict__ srcS,
    const float* __restrict__ norm, const float* __restrict__ h0,
    const float* __restrict__ coef, const int* __restrict__ flags,
    float* __restrict__ z0, float* __restrict__ z1, float* __restrict__ outH)
{
  cg::grid_group grid = cg::this_grid();
  int t = threadIdx.x & 127, sub = threadIdx.x >> 7;
  float* zb[2] = {z0, z1};
  int cur = 1;   // first active step is scaleOnly (flags[16+j]=1 at the top coef), never reads zb[cur]
  for (int j = 10; j >= 1; --j){
    if (!flags[j]) continue;
    bool scaleOnly = flags[16+j] != 0;
    float c = coef[j];
    const float* zin = zb[cur];
    float* zout = zb[cur^1];
    for (int v = blockIdx.x*2 + sub; v < N_NODES; v += gridDim.x*2){
      float acc0 = c * h0[(size_t)v*128 + t];
      if (!scaleOnly){
        int b = rowptr[v], e2 = rowptr[v+1];
        float acc1 = 0.f;
        int i = b;
        for (; i+1 < e2; i += 2){
          acc0 += norm[i]   * zin[(size_t)srcS[i]*128 + t];
          acc1 += norm[i+1] * zin[(size_t)srcS[i+1]*128 + t];
        }
        if (i < e2) acc0 += norm[i]*zin[(size_t)srcS[i]*128 + t];
        acc0 += acc1;
      }
      zout[(size_t)v*128 + t] = acc0;
    }
    grid.sync();
    cur ^= 1;
  }
  if (flags[0]){
    float c = coef[0];
    const float* zin = zb[cur];
    for (int v = blockIdx.x*2 + sub; v < N_NODES; v += gridDim.x*2){
      float acc0 = c * h0[(size_t)v*128 + t];
      int b = rowptr[v], e2 = rowptr[v+1];
      float acc1 = 0.f;
      int i = b;
      for (; i+1 < e2; i += 2){
        acc0 += norm[i]   * zin[(size_t)srcS[i]*128 + t];
        acc1 += norm[i+1] * zin[(size_t)srcS[i+1]*128 + t];
      }
      if (i < e2) acc0 += norm[i]*zin[(size_t)srcS[i]*128 + t];
      outH[(size_t)v*128 + t] = acc0 + acc1;
    }
  }
}

extern "C" void kernel_launch(void* const* d_in, const int* in_sizes, int n_in,
                              void* d_out, int out_size, void* d_ws, size_t ws_size,
                              hipStream_t stream) {
  const float* x1  = (const float*)d_in[0];
  const float* h1  = (const float*)d_in[1];
  const float* x2  = (const float*)d_in[2];
  const float* h2  = (const float*)d_in[3];
  const float* eW1 = (const float*)d_in[4];
  const float* eb1 = (const float*)d_in[5];
  const float* eW2 = (const float*)d_in[6];
  const float* eb2 = (const float*)d_in[7];
  const float* rW1 = (const float*)d_in[8];
  const float* rb1 = (const float*)d_in[9];
  const float* rW2 = (const float*)d_in[10];
  const float* rb2 = (const float*)d_in[11];
  const float* fW1 = (const float*)d_in[12];
  const float* fb1 = (const float*)d_in[13];
  const float* fW2 = (const float*)d_in[14];
  const float* fb2 = (const float*)d_in[15];
  const float* temp= (const float*)d_in[16];
  const int* ei1 = (const int*)d_in[17];
  const int* ei2 = (const int*)d_in[18];

  float* out = (float*)d_out;
  float* outX1 = out;
  float* outH1 = out + 60000;
  float* outX2 = out + 2620000;
  float* outH2 = out + 2680000;
  float* outT1 = out + 5240000;
  float* outT2 = out + 5240011;

  char* ws = (char*)d_ws;
  size_t off = 0;
  auto alloc = [&](size_t bytes)->void*{
    void* p = ws + off; off += (bytes + 255) & ~(size_t)255; return p;
  };
  unsigned short* Pb   = (unsigned short*)alloc((size_t)N_NODES*256*2);  // z1 aliases
  unsigned short* Qb   = (unsigned short*)alloc((size_t)N_NODES*256*2);
  unsigned short* h_bf = (unsigned short*)alloc((size_t)N_NODES*128*2);  // z0 aliases (with t_bf)
  unsigned short* t_bf = (unsigned short*)alloc((size_t)N_NODES*128*2);
  float* h0     = (float*)alloc((size_t)N_NODES*128*4);
  unsigned short* WTbig= (unsigned short*)alloc((size_t)640*128*2);
  unsigned short* WTf2 = (unsigned short*)alloc((size_t)128*128*2);
  float* wbuf   = (float*)alloc((size_t)1536*4);
  float4* x4    = (float4*)alloc((size_t)N_NODES*16);
  int*   srcS   = (int*)  alloc((size_t)N_EDGES*4);
  int*   dstS   = (int*)  alloc((size_t)N_EDGES*4);
  float* normE  = (float*)alloc((size_t)N_EDGES*4);
  float4* rxw   = (float4*)alloc((size_t)N_EDGES*16);
  int*   counts = (int*)  alloc((size_t)N_NODES*4);
  int*   rowptr = (int*)  alloc((size_t)(N_NODES+1)*4);
  float* deg    = (float*)alloc((size_t)N_NODES*4);
  float* coef   = (float*)alloc(256);
  int*   flags  = (int*)  alloc(256);

  float* z0 = (float*)h_bf;   // spans h_bf + t_bf = 10,240,000 B (both dead by horner)
  float* z1 = (float*)Pb;     // 10,240,000 B (dead after k_edge)

  // one-time: polynomial coefficients/flags + T outputs + weight prep
  k_coef<<<1, 64, 0, stream>>>(temp, coef, flags, outT1, outT2);
  k_prep<<<390, 256, 0, stream>>>(eW1, eb1, eW2, rW1, rW2, fW1, fW2, wbuf, WTbig, WTf2);

  const int EB = (N_EDGES + 255)/256;   // 1250
  const int NB = (N_NODES + 255)/256;   // 79

  for (int g = 0; g < 2; ++g){
    const float* x = g ? x2 : x1;
    const float* h = g ? h2 : h1;
    const int* src = g ? ei2 : ei1;
    const int* dst = src + N_EDGES;
    float* outX = g ? outX2 : outX1;
    float* outH = g ? outH2 : outH1;

    // CSR by dst (+ h->bf16 + x->float4 fused with count)
    k_zero   <<<NB, 256, 0, stream>>>(counts, deg);
    k_cnt_cvt<<<2500, 256, 0, stream>>>(dst, counts, h, h_bf, x, x4);
    k_scan   <<<1, 256, 0, stream>>>(counts, rowptr);
    k_fill   <<<EB, 256, 0, stream>>>(src, dst, rowptr, counts, srcS, dstS);

    // [P | Q | t] = h_bf @ WTbig^T, bf16 out
    k_gemm_mfma<<<dim3(313,10), 256, 0, stream>>>(h_bf, WTbig, rb1, fb1, 0,
                                                  nullptr, Pb, Qb, t_bf, nullptr, nullptr);
    // h0 = t_bf @ WTf2^T + fb2 (f32) ; also outH = coef[0]*h0 speculative
    k_gemm_mfma<<<dim3(313,2), 256, 0, stream>>>(t_bf, WTf2, fb2, nullptr, 1,
                                                 h0, nullptr, nullptr, nullptr, coef, outH);

    // per-edge wlap + r (16 lanes/edge); deg atomics gated on flags[0]
    k_edge<<<2500, 256, 0, stream>>>(srcS, dstS, x4, Pb, Qb, wbuf, eb2, rb2,
                                     flags, deg, rxw);
    // fused agg + normE (normE half gated on flags[0])
    k_post<<<6250, 256, 0, stream>>>(rowptr, rxw, x, outX, srcS, dstS, deg,
                                     flags, normE);

    // all Horner steps in one cooperative launch (grid.sync between active steps)
    {
      void* hargs[] = {(void*)&rowptr, (void*)&srcS, (void*)&normE, (void*)&h0,
                       (void*)&coef, (void*)&flags, (void*)&z0, (void*)&z1,
                       (void*)&outH};
      hipLaunchCooperativeKernel((void*)k_horner, dim3(1024), dim3(256),
                                 hargs, 0, stream);
    }
  }
  (void)in_sizes; (void)n_in; (void)out_size; (void)ws_size;
}

// Round 9
// 353.374 us; speedup vs baseline: 1.1397x; 1.1397x over previous
//
#include <hip/hip_runtime.h>
#include <hip/hip_cooperative_groups.h>
#include <math.h>

namespace cg = cooperative_groups;

#define N_NODES 20000     // per graph
#define N_EDGES 320000    // per graph

__device__ __forceinline__ float lrelu(float x){ return x > 0.f ? x : 0.02f*x; }

__device__ __forceinline__ unsigned short f2bf(float f){
  union { float f; unsigned u; } v; v.f = f;
  unsigned r = (v.u + 0x7FFFu + ((v.u >> 16) & 1u)) >> 16;
  return (unsigned short)r;
}
__device__ __forceinline__ float bf2f(unsigned short u){
  union { unsigned u; float f; } v; v.u = ((unsigned)u) << 16; return v.f;
}

typedef __attribute__((ext_vector_type(8))) short bf16x8;
typedef __attribute__((ext_vector_type(4))) float f32x4;
typedef __attribute__((ext_vector_type(8))) unsigned short u16x8;

// ---------------- CSR build (runtime-sized) ----------------
__global__ void k_zero(int* counts, float* deg, int n){
  int i = blockIdx.x*blockDim.x + threadIdx.x;
  if (i < n){ counts[i]=0; deg[i]=0.f; }
}

// per graph: h->bf16 convert + dst-degree count + x->float4 pack, into combined bufs
__global__ void k_cnt_cvt(const int* __restrict__ dst, int* __restrict__ counts,
                          const float* __restrict__ h, unsigned short* __restrict__ h_bf,
                          const float* __restrict__ x, float4* __restrict__ x4,
                          int nodeBase){
  int i = blockIdx.x*256 + threadIdx.x;      // exactly 640000 threads (N_NODES*128/4)
  float4 v = reinterpret_cast<const float4*>(h)[i];
  ushort4 o;
  o.x = f2bf(v.x); o.y = f2bf(v.y); o.z = f2bf(v.z); o.w = f2bf(v.w);
  reinterpret_cast<ushort4*>(h_bf)[(size_t)nodeBase*32 + i] = o;
  if (i < N_EDGES) atomicAdd(&counts[dst[i] + nodeBase], 1);
  if (i < N_NODES) x4[nodeBase + i] = make_float4(x[3*i], x[3*i+1], x[3*i+2], 0.f);
}

__global__ void k_scan(int* __restrict__ counts, int* __restrict__ rowptr, int n){
  __shared__ int part[256];
  int tid = threadIdx.x;
  const int CH = (n + 255)/256;
  int b = tid*CH, e = b+CH; if (e > n) e = n;
  int s = 0;
  for (int i=b;i<e;++i) s += counts[i];
  part[tid] = s; __syncthreads();
  if (tid==0){
    int run=0;
    for (int i=0;i<256;++i){ int t=part[i]; part[i]=run; run+=t; }
    rowptr[n]=run;
  }
  __syncthreads();
  int off = part[tid];
  for (int i=b;i<e;++i){ rowptr[i]=off; off += counts[i]; counts[i]=0; }
}

__global__ void k_fill(const int* __restrict__ src, const int* __restrict__ dst,
                       const int* __restrict__ rowptr, int* __restrict__ cursor,
                       int* __restrict__ srcS, int* __restrict__ dstS, int nodeBase){
  int e = blockIdx.x*blockDim.x + threadIdx.x;
  if (e < N_EDGES){
    int row = dst[e] + nodeBase;
    int pos = atomicAdd(&cursor[row],1);
    int idx = rowptr[row] + pos;
    srcS[idx] = src[e] + nodeBase;
    dstS[idx] = row;
  }
}

// ---------------- weight prep (once) --------------------------------------------
// wbuf: [0,640) eW1 rows 0..4 ; [640,768) base = eb1 + sum_{j>=5} eW1[j]
// (exp(-d2*1e-2j) for j>=5 deviates from 1 by <2e-7 in fp32); [768,896) eW2 ;
// [896,1216) rU padded 16x20 ; [1216,1536) rW2 padded 16x20
__global__ void k_prep(const float* __restrict__ eW1, const float* __restrict__ eb1,
                       const float* __restrict__ eW2v, const float* __restrict__ rW1,
                       const float* __restrict__ rW2, const float* __restrict__ fW1,
                       const float* __restrict__ fW2,
                       float* __restrict__ wbuf,
                       unsigned short* __restrict__ WTbig,
                       unsigned short* __restrict__ WTf2){
  int i = blockIdx.x*blockDim.x + threadIdx.x;   // 99840 total
  if (i < 1536){
    float v;
    if (i < 640) v = eW1[i];
    else if (i < 768){
      int c = i-640; float s = eb1[c];
      for (int j=5;j<10;++j) s += eW1[j*128+c];
      v = s;
    } else if (i < 896) v = eW2v[i-768];
    else if (i < 1216){ int k = i-896;  int l = k/20, jj = k%20;
      v = (jj<16) ? rW1[256*256 + l*16 + jj] : 0.f;
    } else            { int k = i-1216; int l = k/20, jj = k%20;
      v = (jj<16) ? rW2[l*16 + jj] : 0.f;
    }
    wbuf[i] = v;
  } else if (i < 1536 + 81920){
    int j = i - 1536;
    int row = j >> 7, k = j & 127;
    float v = (row < 256) ? rW1[(size_t)k*256 + row]
            : (row < 512) ? rW1[(size_t)(128+k)*256 + (row-256)]
                          : fW1[(size_t)k*128 + (row-512)];
    WTbig[j] = f2bf(v);
  } else if (i < 1536 + 81920 + 16384){
    int j = i - 1536 - 81920; int n = j >> 7, k = j & 127;
    WTf2[j] = f2bf(fW2[(size_t)k*128 + n]);
  }
}

// ---------------- MFMA bf16 GEMM: 64x64 tile, 4 waves, 16x16x32 ----------------
// mode 0 (N=640): col<256 -> Pb=bf16(v+b0); col<512 -> Qb=bf16(v); else Tb=bf16(lrelu(v+b1))
// mode 1 (N=128): h0b = bf16(v+b0); outHspec (f32, exact) = coef[0]*(v+b0), split across outH1/outH2
__global__ __launch_bounds__(256) void k_gemm_mfma(
    const unsigned short* __restrict__ Abf, const unsigned short* __restrict__ WT,
    const float* __restrict__ b0, const float* __restrict__ b1, int mode, int M,
    unsigned short* __restrict__ Pb, unsigned short* __restrict__ Qb,
    unsigned short* __restrict__ Tb, unsigned short* __restrict__ h0b,
    const float* __restrict__ coefp, float* __restrict__ outH1,
    float* __restrict__ outH2, int split)
{
  __shared__ char lA[16384];
  __shared__ char lB[16384];
  int t = threadIdx.x;
  int rbase = blockIdx.x * 64;
  int cbase = blockIdx.y * 64;
  #pragma unroll
  for (int i=0;i<4;++i){
    int c = t + i*256;            // chunk 0..1023, 16B each
    int row = c >> 4, c8 = c & 15;
    int grow = rbase + row; if (grow > M-1) grow = M-1;
    float4 av = *reinterpret_cast<const float4*>(Abf + (size_t)grow*128 + c8*8);
    *reinterpret_cast<float4*>(lA + (((row<<8) + (c8<<4)) ^ ((row&7)<<4))) = av;
    float4 wv = *reinterpret_cast<const float4*>(WT + (size_t)(cbase+row)*128 + c8*8);
    *reinterpret_cast<float4*>(lB + (((row<<8) + (c8<<4)) ^ ((row&7)<<4))) = wv;
  }
  __syncthreads();
  int l = t & 63, w = t >> 6;
  int lr = l & 15;
  int lkb = ((l >> 4) << 3) * 2;          // k byte offset: 0,16,32,48
  int sxor = (lr & 7) << 4;
  f32x4 acc[4];
  #pragma unroll
  for (int tm=0;tm<4;++tm) acc[tm] = (f32x4){0.f,0.f,0.f,0.f};
  #pragma unroll
  for (int ks=0; ks<4; ++ks){
    int kb = ks*64 + lkb;
    bf16x8 bv = *reinterpret_cast<const bf16x8*>(lB + (((((w<<4)+lr)<<8) + kb) ^ sxor));
    #pragma unroll
    for (int tm=0;tm<4;++tm){
      bf16x8 av = *reinterpret_cast<const bf16x8*>(lA + (((((tm<<4)+lr)<<8) + kb) ^ sxor));
      acc[tm] = __builtin_amdgcn_mfma_f32_16x16x32_bf16(av, bv, acc[tm], 0, 0, 0);
    }
  }
  int col = cbase + (w<<4) + lr;
  float bval;
  if (mode==0) bval = (col < 256) ? b0[col] : (col >= 512 ? b1[col-512] : 0.f);
  else         bval = b0[col];
  float c0 = (mode==1) ? coefp[0] : 0.f;
  int rsub = (l >> 4) << 2;
  #pragma unroll
  for (int tm=0;tm<4;++tm){
    #pragma unroll
    for (int r=0;r<4;++r){
      int grow = rbase + (tm<<4) + rsub + r;
      if (grow < M){
        float v = acc[tm][r];
        if (mode==0){
          if (col < 256)      Pb[(size_t)grow*256 + col]       = f2bf(v + bval);
          else if (col < 512) Qb[(size_t)grow*256 + col - 256] = f2bf(v);
          else                Tb[(size_t)grow*128 + col - 512] = f2bf(lrelu(v + bval));
        } else {
          float vb = v + bval;
          h0b[(size_t)grow*128 + col] = f2bf(vb);
          float so = c0 * vb;
          if (grow < split) outH1[(size_t)grow*128 + col] = so;
          else              outH2[(size_t)(grow-split)*128 + col] = so;
        }
      }
    }
  }
}

// ---------------- per-edge: 16 lanes/edge, weights in LDS ----------------
// (256,4): 64 VGPR actual, no spill. ((256,6) forced spill -> 1 GB HBM, round 6.)
__global__ __launch_bounds__(256, 4) void k_edge(
    const int* __restrict__ srcS, const int* __restrict__ dstS,
    const float4* __restrict__ x4,
    const unsigned short* __restrict__ P, const unsigned short* __restrict__ Q,
    const float* __restrict__ wbuf,
    const float* __restrict__ eb2, const float* __restrict__ rb2,
    const int* __restrict__ flags,
    float* __restrict__ deg, float4* __restrict__ rxw, int nEdges)
{
  __shared__ float sw[1536];
  int tid = threadIdx.x;
  for (int i = tid; i < 1536; i += 256) sw[i] = wbuf[i];
  __syncthreads();
  int l = tid & 15;            // lane in 16-lane edge group
  int grp = tid >> 4;          // 0..15 edge slot in block
  float base_r[8], eW2v[8];
  #pragma unroll
  for (int i=0;i<4;++i){
    float2 b = *reinterpret_cast<const float2*>(&sw[640 + 2*l + 32*i]);
    float2 w = *reinterpret_cast<const float2*>(&sw[768 + 2*l + 32*i]);
    base_r[2*i]=b.x; base_r[2*i+1]=b.y; eW2v[2*i]=w.x; eW2v[2*i+1]=w.y;
  }
  float eb2v = eb2[0], rb2v = rb2[0];
  const bool needDeg = flags[0] != 0;   // deg/normE consumed only if any Ax step runs
  for (int e = blockIdx.x*16 + grp; e < nEdges; e += gridDim.x*16){
    int s = srcS[e], d = dstS[e];
    const u16x8* Ps = reinterpret_cast<const u16x8*>(P + (size_t)s*256 + l*16);
    const u16x8* Qd = reinterpret_cast<const u16x8*>(Q + (size_t)d*256 + l*16);
    u16x8 pa = Ps[0], pb = Ps[1];
    u16x8 qa = Qd[0], qb = Qd[1];
    float4 xs = x4[s], xd = x4[d];
    float dx0 = xs.x-xd.x, dx1 = xs.y-xd.y, dx2 = xs.z-xd.z;
    float d2 = dx0*dx0 + dx1*dx1 + dx2*dx2;
    float h[8];
    #pragma unroll
    for (int i=0;i<8;++i) h[i] = base_r[i];
    const float IS[5] = {1.f,1e-2f,1e-4f,1e-6f,1e-8f};
    #pragma unroll
    for (int j=0;j<5;++j){
      float gj = __expf(-d2*IS[j]);
      #pragma unroll
      for (int i=0;i<4;++i){
        float2 w2 = *reinterpret_cast<const float2*>(&sw[j*128 + 2*l + 32*i]);
        h[2*i]   += gj*w2.x;
        h[2*i+1] += gj*w2.y;
      }
    }
    float part = 0.f;
    #pragma unroll
    for (int i=0;i<8;++i) part += lrelu(h[i])*eW2v[i];
    part += __shfl_xor(part,1); part += __shfl_xor(part,2);
    part += __shfl_xor(part,4); part += __shfl_xor(part,8);
    float wlap = part + eb2v; wlap = wlap > 0.f ? wlap : 0.f;
    float acc = 0.f;
    {
      float4 u = *reinterpret_cast<const float4*>(&sw[896 + l*20]);
      float4 w = *reinterpret_cast<const float4*>(&sw[1216 + l*20]);
      acc += lrelu(bf2f((unsigned short)pa[0])+bf2f((unsigned short)qa[0])+wlap*u.x)*w.x;
      acc += lrelu(bf2f((unsigned short)pa[1])+bf2f((unsigned short)qa[1])+wlap*u.y)*w.y;
      acc += lrelu(bf2f((unsigned short)pa[2])+bf2f((unsigned short)qa[2])+wlap*u.z)*w.z;
      acc += lrelu(bf2f((unsigned short)pa[3])+bf2f((unsigned short)qa[3])+wlap*u.w)*w.w;
    }
    {
      float4 u = *reinterpret_cast<const float4*>(&sw[896 + l*20 + 4]);
      float4 w = *reinterpret_cast<const float4*>(&sw[1216 + l*20 + 4]);
      acc += lrelu(bf2f((unsigned short)pa[4])+bf2f((unsigned short)qa[4])+wlap*u.x)*w.x;
      acc += lrelu(bf2f((unsigned short)pa[5])+bf2f((unsigned short)qa[5])+wlap*u.y)*w.y;
      acc += lrelu(bf2f((unsigned short)pa[6])+bf2f((unsigned short)qa[6])+wlap*u.z)*w.z;
      acc += lrelu(bf2f((unsigned short)pa[7])+bf2f((unsigned short)qa[7])+wlap*u.w)*w.w;
    }
    {
      float4 u = *reinterpret_cast<const float4*>(&sw[896 + l*20 + 8]);
      float4 w = *reinterpret_cast<const float4*>(&sw[1216 + l*20 + 8]);
      acc += lrelu(bf2f((unsigned short)pb[0])+bf2f((unsigned short)qb[0])+wlap*u.x)*w.x;
      acc += lrelu(bf2f((unsigned short)pb[1])+bf2f((unsigned short)qb[1])+wlap*u.y)*w.y;
      acc += lrelu(bf2f((unsigned short)pb[2])+bf2f((unsigned short)qb[2])+wlap*u.z)*w.z;
      acc += lrelu(bf2f((unsigned short)pb[3])+bf2f((unsigned short)qb[3])+wlap*u.w)*w.w;
    }
    {
      float4 u = *reinterpret_cast<const float4*>(&sw[896 + l*20 + 12]);
      float4 w = *reinterpret_cast<const float4*>(&sw[1216 + l*20 + 12]);
      acc += lrelu(bf2f((unsigned short)pb[4])+bf2f((unsigned short)qb[4])+wlap*u.x)*w.x;
      acc += lrelu(bf2f((unsigned short)pb[5])+bf2f((unsigned short)qb[5])+wlap*u.y)*w.y;
      acc += lrelu(bf2f((unsigned short)pb[6])+bf2f((unsigned short)qb[6])+wlap*u.z)*w.z;
      acc += lrelu(bf2f((unsigned short)pb[7])+bf2f((unsigned short)qb[7])+wlap*u.w)*w.w;
    }
    acc += __shfl_xor(acc,1); acc += __shfl_xor(acc,2);
    acc += __shfl_xor(acc,4); acc += __shfl_xor(acc,8);
    if (l==0){
      float r = acc + rb2v;
      if (needDeg) atomicAdd(&deg[s], wlap);
      rxw[e] = make_float4(r*dx0, r*dx1, r*dx2, wlap);
    }
  }
}

// ---------------- fused post: agg (blocks < aggBlocks) + normE (rest) ----------
__global__ __launch_bounds__(256) void k_post(const int* __restrict__ rowptr,
    const float4* __restrict__ rxw, const float4* __restrict__ x4,
    float* __restrict__ outX1, float* __restrict__ outX2, int split,
    const int* __restrict__ srcS, const int* __restrict__ dstS,
    const float* __restrict__ deg, const int* __restrict__ flags,
    float* __restrict__ norm, int nNodes, int aggBlocks, int nEdges)
{
  if ((int)blockIdx.x < aggBlocks){
    int lane = threadIdx.x & 63;
    int v = blockIdx.x*4 + (threadIdx.x>>6);
    if (v >= nNodes) return;
    int b = rowptr[v], e = rowptr[v+1];
    float a0=0.f,a1=0.f,a2=0.f;
    for (int i=b+lane;i<e;i+=64){ float4 f = rxw[i]; a0+=f.x; a1+=f.y; a2+=f.z; }
    #pragma unroll
    for (int m=1;m<64;m<<=1){ a0+=__shfl_xor(a0,m); a1+=__shfl_xor(a1,m); a2+=__shfl_xor(a2,m); }
    if (lane==0){
      int cnt = e-b; if (cnt < 1) cnt = 1;
      float inv = 1.0f/(float)cnt;
      float4 xv = x4[v];
      float* o = (v < split) ? (outX1 + (size_t)v*3) : (outX2 + (size_t)(v-split)*3);
      o[0] = xv.x + a0*inv;
      o[1] = xv.y + a1*inv;
      o[2] = xv.z + a2*inv;
    }
  } else {
    if (!flags[0]) return;   // normE consumed only by Ax steps
    int e = (blockIdx.x-aggBlocks)*256 + threadIdx.x;
    if (e < nEdges){
      float ds = deg[srcS[e]], dd = deg[dstS[e]];
      float is = ds > 0.f ? rsqrtf(ds) : 0.f;
      float id = dd > 0.f ? rsqrtf(dd) : 0.f;
      norm[e] = is * rxw[e].w * id;
    }
  }
}

// polynomial coefficients + run flags (see round-7 notes)
__global__ void k_coef(const float* __restrict__ temp, float* __restrict__ coef,
                       int* __restrict__ flags,
                       float* __restrict__ outT1, float* __restrict__ outT2){
  if (threadIdx.x == 0 && blockIdx.x == 0){
    const double binom[11] = {1,10,45,120,210,252,210,120,45,10,1};
    double a[11]; for (int j=0;j<11;++j) a[j]=0.0;
    for (int m=0;m<=10;++m){
      double p[11]; p[0]=1.0; for (int j=1;j<11;++j) p[j]=0.0;
      for (int r2=0;r2<10-m;++r2) for (int j=10;j>=1;--j) p[j]+=p[j-1];
      for (int r2=0;r2<m;++r2)    for (int j=10;j>=1;--j) p[j]-=p[j-1];
      float t = temp[m];
      double c = (binom[m]/1024.0) * (t > 0.f ? (double)t : 0.0);
      for (int j=0;j<11;++j) a[j]+=c*p[j];
    }
    for (int j=0;j<11;++j) coef[j]=(float)a[j];
    double sIn = 0.0;
    for (int j=10;j>=0;--j){
      double sOut = sIn + fabs(a[j]);
      flags[j]    = (j==0) ? ((sIn != 0.0) ? 1 : 0) : ((sOut != 0.0) ? 1 : 0);
      flags[16+j] = (sIn  == 0.0) ? 1 : 0;
      sIn = sOut;
    }
  }
  int i = threadIdx.x;
  if (blockIdx.x==0 && i < 11){ float t = temp[i]; t = t>0.f?t:0.f; outT1[i]=t; outT2[i]=t; }
}

// ---------------- cooperative Horner over combined graphs ----------------
__global__ __launch_bounds__(256) void k_horner(
    const int* __restrict__ rowptr, const int* __restrict__ srcS,
    const float* __restrict__ norm, const unsigned short* __restrict__ h0b,
    const float* __restrict__ coef, const int* __restrict__ flags,
    float* __restrict__ z0, float* __restrict__ z1,
    float* __restrict__ outH1, float* __restrict__ outH2, int split, int nNodes)
{
  cg::grid_group grid = cg::this_grid();
  int t = threadIdx.x & 127, sub = threadIdx.x >> 7;
  float* zb[2] = {z0, z1};
  int cur = 1;   // first active step is scaleOnly, never reads zb[cur]
  for (int j = 10; j >= 1; --j){
    if (!flags[j]) continue;
    bool scaleOnly = flags[16+j] != 0;
    float c = coef[j];
    const float* zin = zb[cur];
    float* zout = zb[cur^1];
    for (int v = blockIdx.x*2 + sub; v < nNodes; v += gridDim.x*2){
      float acc0 = c * bf2f(h0b[(size_t)v*128 + t]);
      if (!scaleOnly){
        int b = rowptr[v], e2 = rowptr[v+1];
        float acc1 = 0.f;
        int i = b;
        for (; i+1 < e2; i += 2){
          acc0 += norm[i]   * zin[(size_t)srcS[i]*128 + t];
          acc1 += norm[i+1] * zin[(size_t)srcS[i+1]*128 + t];
        }
        if (i < e2) acc0 += norm[i]*zin[(size_t)srcS[i]*128 + t];
        acc0 += acc1;
      }
      zout[(size_t)v*128 + t] = acc0;
    }
    grid.sync();
    cur ^= 1;
  }
  if (flags[0]){
    float c = coef[0];
    const float* zin = zb[cur];
    for (int v = blockIdx.x*2 + sub; v < nNodes; v += gridDim.x*2){
      float acc0 = c * bf2f(h0b[(size_t)v*128 + t]);
      int b = rowptr[v], e2 = rowptr[v+1];
      float acc1 = 0.f;
      int i = b;
      for (; i+1 < e2; i += 2){
        acc0 += norm[i]   * zin[(size_t)srcS[i]*128 + t];
        acc1 += norm[i+1] * zin[(size_t)srcS[i+1]*128 + t];
      }
      if (i < e2) acc0 += norm[i]*zin[(size_t)srcS[i]*128 + t];
      acc0 += acc1;
      float* o = (v < split) ? (outH1 + (size_t)v*128) : (outH2 + (size_t)(v-split)*128);
      o[t] = acc0;
    }
  }
}

extern "C" void kernel_launch(void* const* d_in, const int* in_sizes, int n_in,
                              void* d_out, int out_size, void* d_ws, size_t ws_size,
                              hipStream_t stream) {
  const float* x1  = (const float*)d_in[0];
  const float* h1  = (const float*)d_in[1];
  const float* x2  = (const float*)d_in[2];
  const float* h2  = (const float*)d_in[3];
  const float* eW1 = (const float*)d_in[4];
  const float* eb1 = (const float*)d_in[5];
  const float* eW2 = (const float*)d_in[6];
  const float* eb2 = (const float*)d_in[7];
  const float* rW1 = (const float*)d_in[8];
  const float* rb1 = (const float*)d_in[9];
  const float* rW2 = (const float*)d_in[10];
  const float* rb2 = (const float*)d_in[11];
  const float* fW1 = (const float*)d_in[12];
  const float* fb1 = (const float*)d_in[13];
  const float* fW2 = (const float*)d_in[14];
  const float* fb2 = (const float*)d_in[15];
  const float* temp= (const float*)d_in[16];
  const int* ei1 = (const int*)d_in[17];
  const int* ei2 = (const int*)d_in[18];

  float* out = (float*)d_out;
  float* outX1 = out;
  float* outH1 = out + 60000;
  float* outX2 = out + 2620000;
  float* outH2 = out + 2680000;
  float* outT1 = out + 5240000;
  float* outT2 = out + 5240011;

  // ---- workspace plan: try batched (both graphs combined), else per-graph ----
  auto needBytes = [](size_t NT, size_t ET)->size_t{
    auto al = [](size_t b){ return (b + 255) & ~(size_t)255; };
    size_t o = 0;
    o += al(NT*512);      // Pb (z1 alias)
    o += al(NT*512);      // Qb
    o += al(NT*256);      // h_bf  (z0 alias, with t_bf)
    o += al(NT*256);      // t_bf
    o += al(NT*256);      // h0b (bf16)
    o += al(640*128*2);   // WTbig
    o += al(128*128*2);   // WTf2
    o += al(1536*4);      // wbuf
    o += al(NT*16);       // x4
    o += al(ET*4);        // srcS
    o += al(ET*4);        // dstS
    o += al(ET*4);        // normE
    o += al(ET*16);       // rxw
    o += al(NT*4);        // counts
    o += al((NT+1)*4);    // rowptr
    o += al(NT*4);        // deg
    o += al(256) + al(256); // coef, flags
    return o;
  };
  const bool batched = ws_size >= needBytes(2*N_NODES, 2*N_EDGES);
  const int NT = batched ? 2*N_NODES : N_NODES;
  const int ET = batched ? 2*N_EDGES : N_EDGES;

  char* ws = (char*)d_ws;
  size_t off = 0;
  auto alloc = [&](size_t bytes)->void*{
    void* p = ws + off; off += (bytes + 255) & ~(size_t)255; return p;
  };
  unsigned short* Pb   = (unsigned short*)alloc((size_t)NT*512);
  unsigned short* Qb   = (unsigned short*)alloc((size_t)NT*512);
  unsigned short* h_bf = (unsigned short*)alloc((size_t)NT*256);
  unsigned short* t_bf = (unsigned short*)alloc((size_t)NT*256);
  unsigned short* h0b  = (unsigned short*)alloc((size_t)NT*256);
  unsigned short* WTbig= (unsigned short*)alloc((size_t)640*128*2);
  unsigned short* WTf2 = (unsigned short*)alloc((size_t)128*128*2);
  float* wbuf   = (float*)alloc((size_t)1536*4);
  float4* x4    = (float4*)alloc((size_t)NT*16);
  int*   srcS   = (int*)  alloc((size_t)ET*4);
  int*   dstS   = (int*)  alloc((size_t)ET*4);
  float* normE  = (float*)alloc((size_t)ET*4);
  float4* rxw   = (float4*)alloc((size_t)ET*16);
  int*   counts = (int*)  alloc((size_t)NT*4);
  int*   rowptr = (int*)  alloc((size_t)(NT+1)*4);
  float* deg    = (float*)alloc((size_t)NT*4);
  float* coef   = (float*)alloc(256);
  int*   flags  = (int*)  alloc(256);

  float* z0 = (float*)h_bf;   // spans h_bf+t_bf = NT*512 B (dead by horner)
  float* z1 = (float*)Pb;     // NT*512 B (dead after k_edge)

  // one-time
  k_coef<<<1, 64, 0, stream>>>(temp, coef, flags, outT1, outT2);
  k_prep<<<390, 256, 0, stream>>>(eW1, eb1, eW2, rW1, rW2, fW1, fW2, wbuf, WTbig, WTf2);

  const int ZB = (NT + 255)/256;
  const int gemmRows = (NT + 63)/64;
  const int aggBlocks = (NT + 3)/4;
  const int normBlocks = (ET + 255)/256;

  if (batched){
    k_zero   <<<ZB, 256, 0, stream>>>(counts, deg, NT);
    k_cnt_cvt<<<2500, 256, 0, stream>>>(ei1 + N_EDGES, counts, h1, h_bf, x1, x4, 0);
    k_cnt_cvt<<<2500, 256, 0, stream>>>(ei2 + N_EDGES, counts, h2, h_bf, x2, x4, N_NODES);
    k_scan   <<<1, 256, 0, stream>>>(counts, rowptr, NT);
    k_fill   <<<1250, 256, 0, stream>>>(ei1, ei1 + N_EDGES, rowptr, counts, srcS, dstS, 0);
    k_fill   <<<1250, 256, 0, stream>>>(ei2, ei2 + N_EDGES, rowptr, counts, srcS, dstS, N_NODES);

    k_gemm_mfma<<<dim3(gemmRows,10), 256, 0, stream>>>(h_bf, WTbig, rb1, fb1, 0, NT,
                                                       Pb, Qb, t_bf, nullptr,
                                                       nullptr, nullptr, nullptr, 0);
    k_gemm_mfma<<<dim3(gemmRows,2), 256, 0, stream>>>(t_bf, WTf2, fb2, nullptr, 1, NT,
                                                      nullptr, nullptr, nullptr, h0b,
                                                      coef, outH1, outH2, N_NODES);

    k_edge<<<5000, 256, 0, stream>>>(srcS, dstS, x4, Pb, Qb, wbuf, eb2, rb2,
                                     flags, deg, rxw, ET);
    k_post<<<aggBlocks + normBlocks, 256, 0, stream>>>(rowptr, rxw, x4,
                                     outX1, outX2, N_NODES, srcS, dstS, deg,
                                     flags, normE, NT, aggBlocks, ET);
    {
      int split = N_NODES, nn = NT;
      void* hargs[] = {(void*)&rowptr, (void*)&srcS, (void*)&normE, (void*)&h0b,
                       (void*)&coef, (void*)&flags, (void*)&z0, (void*)&z1,
                       (void*)&outH1, (void*)&outH2, (void*)&split, (void*)&nn};
      hipLaunchCooperativeKernel((void*)k_horner, dim3(1024), dim3(256),
                                 hargs, 0, stream);
    }
  } else {
    for (int g = 0; g < 2; ++g){
      const float* x = g ? x2 : x1;
      const float* h = g ? h2 : h1;
      const int* src = g ? ei2 : ei1;
      const int* dst = src + N_EDGES;
      float* outX = g ? outX2 : outX1;
      float* outH = g ? outH2 : outH1;

      k_zero   <<<ZB, 256, 0, stream>>>(counts, deg, NT);
      k_cnt_cvt<<<2500, 256, 0, stream>>>(dst, counts, h, h_bf, x, x4, 0);
      k_scan   <<<1, 256, 0, stream>>>(counts, rowptr, NT);
      k_fill   <<<1250, 256, 0, stream>>>(src, dst, rowptr, counts, srcS, dstS, 0);

      k_gemm_mfma<<<dim3(gemmRows,10), 256, 0, stream>>>(h_bf, WTbig, rb1, fb1, 0, NT,
                                                         Pb, Qb, t_bf, nullptr,
                                                         nullptr, nullptr, nullptr, 0);
      k_gemm_mfma<<<dim3(gemmRows,2), 256, 0, stream>>>(t_bf, WTf2, fb2, nullptr, 1, NT,
                                                        nullptr, nullptr, nullptr, h0b,
                                                        coef, outH, outH, NT);

      k_edge<<<2500, 256, 0, stream>>>(srcS, dstS, x4, Pb, Qb, wbuf, eb2, rb2,
                                       flags, deg, rxw, ET);
      k_post<<<aggBlocks + normBlocks, 256, 0, stream>>>(rowptr, rxw, x4,
                                       outX, outX, NT, srcS, dstS, deg,
                                       flags, normE, NT, aggBlocks, ET);
      {
        int split = NT, nn = NT;
        void* hargs[] = {(void*)&rowptr, (void*)&srcS, (void*)&normE, (void*)&h0b,
                         (void*)&coef, (void*)&flags, (void*)&z0, (void*)&z1,
                         (void*)&outH, (void*)&outH, (void*)&split, (void*)&nn};
        hipLaunchCooperativeKernel((void*)k_horner, dim3(1024), dim3(256),
                                   hargs, 0, stream);
      }
    }
  }
  (void)in_sizes; (void)n_in; (void)out_size; (void)ws_size;
}